// Round 6
// baseline (319.888 us; speedup 1.0000x reference)
//
#include <hip/hip_runtime.h>
#include <hip/hip_bf16.h>

// Problem constants (fixed by the reference)
#define TOTAL   8192
#define DMODEL  1024
#define NHEADS  16
#define NSEQ    8
#define DH      64
// attention block (h,b): contiguous 1024x64 chunk at flat offset hb*65536

typedef float  f32x4 __attribute__((ext_vector_type(4)));
typedef short  s16x8 __attribute__((ext_vector_type(8)));   // 8 bf16 (4 VGPRs)
typedef short  s16x4 __attribute__((ext_vector_type(4)));   // 4 bf16 (2 VGPRs)
typedef unsigned short u16;
typedef u16    u16x8 __attribute__((ext_vector_type(8)));

__device__ __forceinline__ u16 f2bf_rne(float x) {
  union { float f; unsigned u; } v; v.f = x;
  unsigned r = v.u + 0x7FFFu + ((v.u >> 16) & 1u);
  return (u16)(r >> 16);
}

// async global->LDS, 16 B per lane; LDS dest = wave-uniform base + lane*16
__device__ __forceinline__ void async_cp16(const u16* g, u16* l) {
  __builtin_amdgcn_global_load_lds(
      (const __attribute__((address_space(1))) unsigned int*)g,
      (__attribute__((address_space(3))) unsigned int*)l, 16, 0, 0);
}

// 16x16x16 bf16 MFMA (A,B = 4 bf16 / 2 VGPRs). Builtin name varies across
// ROCm versions; hedge with __has_builtin, fall back to inline asm.
__device__ __forceinline__ f32x4 mfma16_bf16(s16x4 a, s16x4 b, f32x4 c) {
#if __has_builtin(__builtin_amdgcn_mfma_f32_16x16x16bf16_1k)
  return __builtin_amdgcn_mfma_f32_16x16x16bf16_1k(a, b, c, 0, 0, 0);
#elif __has_builtin(__builtin_amdgcn_mfma_f32_16x16x16_bf16)
  return __builtin_amdgcn_mfma_f32_16x16x16_bf16(a, b, c, 0, 0, 0);
#else
  f32x4 d;
  asm("v_mfma_f32_16x16x16_bf16 %0, %1, %2, %3"
      : "=v"(d) : "v"(a), "v"(b), "v"(c));
  return d;
#endif
}

// ---------------------------------------------------------------------------
// 0. f32 -> bf16 (RNE) converters
// ---------------------------------------------------------------------------
__device__ __forceinline__ void cvt8_one(const float* __restrict__ src,
                                         u16* __restrict__ dst, long i) {
  float4 a = *reinterpret_cast<const float4*>(src + i);
  float4 b = *reinterpret_cast<const float4*>(src + i + 4);
  u16x8 o;
  o[0] = f2bf_rne(a.x); o[1] = f2bf_rne(a.y); o[2] = f2bf_rne(a.z); o[3] = f2bf_rne(a.w);
  o[4] = f2bf_rne(b.x); o[5] = f2bf_rne(b.y); o[6] = f2bf_rne(b.z); o[7] = f2bf_rne(b.w);
  *reinterpret_cast<u16x8*>(dst + i) = o;
}

__global__ __launch_bounds__(256) void cvt8(const float* __restrict__ src,
                                            u16* __restrict__ dst) {
  cvt8_one(src, dst, ((long)blockIdx.x * 256 + threadIdx.x) * 8);
}

// 4 weight matrices in one launch; blockIdx.y picks the matrix
__global__ __launch_bounds__(256) void cvt8_w4(const float* __restrict__ w0,
                                               const float* __restrict__ w1,
                                               const float* __restrict__ w2,
                                               const float* __restrict__ w3,
                                               u16* __restrict__ dst) {
  const float* srcs[4] = {w0, w1, w2, w3};
  cvt8_one(srcs[blockIdx.y], dst + (long)blockIdx.y * (DMODEL * (long)DMODEL),
           ((long)blockIdx.x * 256 + threadIdx.x) * 8);
}

// 3 X inputs in one launch; blockIdx.y picks
__global__ __launch_bounds__(256) void cvt8_x3(const float* __restrict__ x0,
                                               const float* __restrict__ x1,
                                               const float* __restrict__ x2,
                                               u16* __restrict__ dst) {
  const float* srcs[3] = {x0, x1, x2};
  cvt8_one(srcs[blockIdx.y], dst + (long)blockIdx.y * (TOTAL * (long)DMODEL),
           ((long)blockIdx.x * 256 + threadIdx.x) * 8);
}

// ---------------------------------------------------------------------------
// 1. NT GEMM, 8-phase-lite pipeline (T1+T2+T3/T4+T5):
//    BM=256, BN=128, BK=64. 512 threads = 8 waves (4M x 2N), 64x64 per wave.
//    3-stage LDS pipeline (144 KiB): stage tile t+2 while computing tile t.
//    Counted s_waitcnt vmcnt(6) per K-tile (never 0 in the main loop).
//    T2 XOR-swizzle byte^=(row&7)<<4 on ds_read; inverse swizzle pre-applied
//    to the per-lane GLOBAL source so global_load_lds dest stays linear
//    (rule 21: both-sides-or-neither).
// ---------------------------------------------------------------------------
// LDS per buffer: A 256x64 u16 = 16384, B 128x64 u16 = 8192 -> 24576 u16.
template<bool OUT_BF16>
__device__ __forceinline__ void gemm256_core(const u16* __restrict__ A,
                                             const u16* __restrict__ B,
                                             const float* __restrict__ bias,
                                             void* __restrict__ Cp,
                                             long bm0, long bn0, u16* lds) {
  const int tid  = threadIdx.x;
  const int lane = tid & 63;
  const int wv   = tid >> 6;        // 0..7
  const int quad = lane >> 4;
  const int m16  = lane & 15;
  const int wm   = (wv >> 1) * 64;  // 4 M-waves
  const int wn   = (wv & 1) * 64;   // 2 N-waves

  // --- staging addresses -------------------------------------------------
  // global_load_lds writes LDS linearly at base + lane*16. Lane L's 16B
  // lands at physical row (L>>3), slot (L&7) of its 8-row line; the READ
  // swizzle is slot^(row&7), so the SOURCE fetches slot (L&7)^(L>>3).
  const int l8   = lane >> 3;
  const int slot = (lane & 7) ^ l8;
  const long g_lane = (long)l8 * DMODEL + slot * 8;
  const u16* Ap = A + (bm0 + wv * 32) * (long)DMODEL + g_lane;  // 4 lines x 8 rows
  const u16* Bp = B + (bn0 + wv * 16) * (long)DMODEL + g_lane;  // 2 lines x 8 rows
  u16* ldsA = lds + wv * (4 * 512);
  u16* ldsB = lds + 16384 + wv * (2 * 512);

  // --- frag read offsets (u16 units), T2-swizzled ------------------------
  // logical (row, col-byte c) lives at row*128 + (c ^ ((row&7)<<4))
  const int swz0 = ((quad * 16)      ^ ((m16 & 7) << 4)) >> 1;  // k-half 0
  const int swz1 = ((64 + quad * 16) ^ ((m16 & 7) << 4)) >> 1;  // k-half 1
  const int aro = (wm + m16) * 64;
  const int bro = 16384 + (wn + m16) * 64;

  f32x4 acc[4][4] = {};

#define STAGE_A(buf, kt) do {                                       \
    _Pragma("unroll")                                               \
    for (int al = 0; al < 4; al++)                                  \
      async_cp16(Ap + (long)(kt) * 64 + al * (8 * DMODEL),          \
                 ldsA + (buf) * 24576 + al * 512);                  \
  } while (0)
#define STAGE_B(buf, kt) do {                                       \
    _Pragma("unroll")                                               \
    for (int bl = 0; bl < 2; bl++)                                  \
      async_cp16(Bp + (long)(kt) * 64 + bl * (8 * DMODEL),          \
                 ldsB + (buf) * 24576 + bl * 512);                  \
  } while (0)

  // prologue: tiles 0 and 1 in flight (12 loads)
  STAGE_A(0, 0); STAGE_B(0, 0);
  STAGE_A(1, 1); STAGE_B(1, 1);

  #pragma unroll
  for (int t = 0; t < 16; t++) {           // NT = DMODEL/64 = 16
    const int cur = t % 3;
    const int stg = (t + 2) % 3;
    // retire tile t's 6 loads (tile t+1's 6 stay in flight); align waves
    if (t < 15) asm volatile("s_waitcnt vmcnt(6)" ::: "memory");
    else        asm volatile("s_waitcnt vmcnt(0)" ::: "memory");
    __builtin_amdgcn_s_barrier();
    asm volatile("" ::: "memory");         // no LDS read hoists above barrier

    const u16* lb = lds + cur * 24576;

    // ---- phase A: B frags + A frags 0..1, MFMA quadrant M01 ----
    if (t < 14) STAGE_A(stg, t + 2);       // buf stg last read at t-1: safe
    s16x8 bf[4][2], af[2][2];
    #pragma unroll
    for (int n = 0; n < 4; n++) {
      bf[n][0] = *(const s16x8*)&lb[bro + n * 1024 + swz0];
      bf[n][1] = *(const s16x8*)&lb[bro + n * 1024 + swz1];
    }
    #pragma unroll
    for (int i = 0; i < 2; i++) {
      af[i][0] = *(const s16x8*)&lb[aro + i * 1024 + swz0];
      af[i][1] = *(const s16x8*)&lb[aro + i * 1024 + swz1];
    }
    asm volatile("s_waitcnt lgkmcnt(0)" ::: "memory");
    __builtin_amdgcn_sched_barrier(0);     // rule 18: pin MFMA after the wait
    __builtin_amdgcn_s_setprio(1);
    #pragma unroll
    for (int i = 0; i < 2; i++)
      #pragma unroll
      for (int n = 0; n < 4; n++) {
        acc[i][n] = __builtin_amdgcn_mfma_f32_16x16x32_bf16(af[i][0], bf[n][0], acc[i][n], 0, 0, 0);
        acc[i][n] = __builtin_amdgcn_mfma_f32_16x16x32_bf16(af[i][1], bf[n][1], acc[i][n], 0, 0, 0);
      }
    __builtin_amdgcn_s_setprio(0);
    __builtin_amdgcn_s_barrier();

    // ---- phase B: A frags 2..3 (B frags reused), MFMA quadrant M23 ----
    if (t < 14) STAGE_B(stg, t + 2);
    s16x8 ag[2][2];
    #pragma unroll
    for (int i = 0; i < 2; i++) {
      ag[i][0] = *(const s16x8*)&lb[aro + (i + 2) * 1024 + swz0];
      ag[i][1] = *(const s16x8*)&lb[aro + (i + 2) * 1024 + swz1];
    }
    asm volatile("s_waitcnt lgkmcnt(0)" ::: "memory");
    __builtin_amdgcn_sched_barrier(0);
    __builtin_amdgcn_s_setprio(1);
    #pragma unroll
    for (int i = 0; i < 2; i++)
      #pragma unroll
      for (int n = 0; n < 4; n++) {
        acc[i + 2][n] = __builtin_amdgcn_mfma_f32_16x16x32_bf16(ag[i][0], bf[n][0], acc[i + 2][n], 0, 0, 0);
        acc[i + 2][n] = __builtin_amdgcn_mfma_f32_16x16x32_bf16(ag[i][1], bf[n][1], acc[i + 2][n], 0, 0, 0);
      }
    __builtin_amdgcn_s_setprio(0);
    // no trailing barrier: next iteration's vmcnt+barrier is the fence
  }
#undef STAGE_A
#undef STAGE_B

  // Epilogue. C/D layout (verified m89/m91): col = lane&15, row = quad*4 + reg.
  #pragma unroll
  for (int n = 0; n < 4; n++) {
    const long col = bn0 + wn + n * 16 + m16;
    const float bj = bias[col];
    #pragma unroll
    for (int i = 0; i < 4; i++) {
      const long row0 = bm0 + wm + i * 16 + quad * 4;
      #pragma unroll
      for (int r = 0; r < 4; r++) {
        float v = acc[i][n][r] + bj;
        if constexpr (OUT_BF16)
          ((u16*)Cp)[(row0 + r) * DMODEL + col] = f2bf_rne(v);
        else
          ((float*)Cp)[(row0 + r) * DMODEL + col] = v;
      }
    }
  }
}

// T1 XCD swizzle: dispatch index % 8 = XCD; give each XCD a contiguous
// 32-wg chunk = 4 M-panels x all 8 N-blocks (A 2MB + B 2MB fits 4MB L2).
__device__ __forceinline__ void decode_wg(int x, long& bm0, long& bn0) {
  const int wg = (x & 7) * 32 + (x >> 3);   // bijective: 256 = 8*32
  bm0 = (long)(wg >> 3) * 256;              // 32 M-blocks
  bn0 = (long)(wg & 7) * 128;               // 8 N-blocks
}

template<bool OUT_BF16>
__global__ __launch_bounds__(512, 2) void gemm256_nt(const u16* __restrict__ A,
                                                     const u16* __restrict__ B,
                                                     const float* __restrict__ bias,
                                                     void* __restrict__ Cp) {
  __shared__ __align__(1024) u16 lds[3 * 24576];  // 144 KiB
  long bm0, bn0;
  decode_wg(blockIdx.x, bm0, bn0);
  gemm256_core<OUT_BF16>(A, B, bias, Cp, bm0, bn0, lds);
}

// Fused Q/K/V projection: blockIdx.y picks (X, W, bias, out). 768 blocks
// = 3 perfect rounds on 256 CUs.
__global__ __launch_bounds__(512, 2) void gemm256_qkv(const u16* __restrict__ X3,
                                                      const u16* __restrict__ W3,
                                                      const float* __restrict__ bq,
                                                      const float* __restrict__ bk,
                                                      const float* __restrict__ bv,
                                                      u16* __restrict__ QKV) {
  __shared__ __align__(1024) u16 lds[3 * 24576];
  const int z = blockIdx.y;
  const float* bias = (z == 0) ? bq : (z == 1) ? bk : bv;
  long bm0, bn0;
  decode_wg(blockIdx.x, bm0, bn0);
  gemm256_core<true>(X3 + (long)z * (TOTAL * (long)DMODEL),
                     W3 + (long)z * (DMODEL * (long)DMODEL),
                     bias,
                     QKV + (long)z * (TOTAL * (long)DMODEL),
                     bm0, bn0, lds);
}

// ---------------------------------------------------------------------------
// 2. Per-block V transpose: Vbf natural (hb-block rows k, cols dh) ->
//    Vt[hb][dh][k] so attention PV B-frags are contiguous reads.
// ---------------------------------------------------------------------------
__global__ __launch_bounds__(256) void transpose_v(const u16* __restrict__ Vbf,
                                                   u16* __restrict__ Vt) {
  constexpr int TP = 72;
  __shared__ u16 tile[64 * TP];  // tile[dh][k]
  const int tid = threadIdx.x;
  const long base = (long)blockIdx.y * 65536;  // hb block
  const int kt = blockIdx.x;                   // 16 k-tiles of 64
  {
    int k = tid >> 2, dh0 = (tid & 3) * 16;
    const u16* g = Vbf + base + (long)(kt * 64 + k) * 64 + dh0;
    u16x8 a = ((const u16x8*)g)[0];
    u16x8 b = ((const u16x8*)g)[1];
    #pragma unroll
    for (int i = 0; i < 8; i++) tile[(dh0 + i) * TP + k] = a[i];
    #pragma unroll
    for (int i = 0; i < 8; i++) tile[(dh0 + 8 + i) * TP + k] = b[i];
  }
  __syncthreads();
  {
    int dh = tid >> 2, k0 = (tid & 3) * 16;
    u16x8 a = *(const u16x8*)&tile[dh * TP + k0];
    u16x8 b = *(const u16x8*)&tile[dh * TP + k0 + 8];
    u16* g = Vt + base + (long)dh * 1024 + kt * 64 + k0;
    ((u16x8*)g)[0] = a;
    ((u16x8*)g)[1] = b;
  }
}

// ---------------------------------------------------------------------------
// 3. Attention: per (hb, 128-row q-tile). 4 waves x 32 Q-rows (2 groups of 16).
//    K/V tiles of 64 in LDS (pitch 72). No max-subtraction (scores bounded):
//    acc_o = sum e^(s*scale)*V, den via ones-MFMA.
//    KEY IDENTITY (removes the E LDS round-trip entirely): swapped QK^T
//    (A=K, B=Q) over a 16-kv subtile leaves lane(quad,m16) holding
//    S[q=m16][kv=quad*4+r], r=0..3 — exactly the A-fragment layout of
//    v_mfma_f32_16x16x16_bf16 (A[row=m16][k=quad*4+j]). So exp2 + RNE-pack
//    into 2 VGPRs feeds PV DIRECTLY in-register. PV B-frag = one contiguous
//    ds_read_b64 from Vs[dh][kv] (B[k=mt*16+quad*4+j][col=n*16+m16]).
//    Per tile: 8 independent (mt,g) chains, no lgkmcnt drain, no Es buffer
//    (LDS 36.9KB -> 18.4KB => 2x blocks/CU). Accumulator layouts identical
//    to the verified round-5 epilogue (D: row=q=quad*4+r, col=m16).
//    T14: next tile's K/V global loads issue right after the staging barrier.
//    Grid: x = hb (128) -> same-hb blocks land on one XCD (128 % 8 == 0).
// ---------------------------------------------------------------------------
__global__ __launch_bounds__(256) void attn_kernel(const u16* __restrict__ Qbf,
                                                   const u16* __restrict__ Kbf,
                                                   const u16* __restrict__ Vt,
                                                   u16* __restrict__ Obf) {
  constexpr int KP = 72;  // uniform pitch
  __shared__ u16 Ks[64 * KP];        // Ks[kv][dh]
  __shared__ u16 Vs[64 * KP];        // Vs[dh][kv]
  const int tid  = threadIdx.x;
  const int lane = tid & 63;
  const int wv   = tid >> 6;
  const int quad = lane >> 4;
  const int m16  = lane & 15;
  const int qt   = blockIdx.y;                 // 8 q-tiles of 128
  const long base = (long)blockIdx.x * 65536;  // hb block

  const int qrow0 = qt * 128 + wv * 32;
  s16x8 aq[2][2];
  #pragma unroll
  for (int g = 0; g < 2; g++)
    #pragma unroll
    for (int s = 0; s < 2; s++)
      aq[g][s] = *(const s16x8*)(Qbf + base + (long)(qrow0 + g * 16 + m16) * 64 + s * 32 + quad * 8);

  f32x4 acc_o[2][4] = {};
  f32x4 acc_d[2] = {};

  // ones B-frag for 16x16x16 den-MFMA: B[k][0]=1 -> lanes with m16==0 hold 1
  union { u16 u[4]; s16x4 s; } onesu;
  u16 ov = (m16 == 0) ? (u16)0x3F80 : (u16)0;
  #pragma unroll
  for (int i = 0; i < 4; i++) onesu.u[i] = ov;
  const s16x4 bones4 = onesu.s;

  const float SC = 0.125f * 1.44269504088896340736f;  // scale * log2(e)
  const int sr = tid >> 2;
  const int sk = (tid & 3) * 16;

  // T14 prefetch registers (tile nt staged in regs across the barrier)
  const u16* gK = Kbf + base + (long)sr * 64 + sk;     // + nt*4096
  const u16* gV = Vt  + base + (long)sr * 1024 + sk;   // + nt*64
  u16x8 kra = ((const u16x8*)gK)[0], krb = ((const u16x8*)gK)[1];
  u16x8 vra = ((const u16x8*)gV)[0], vrb = ((const u16x8*)gV)[1];

  for (int nt = 0; nt < 16; nt++) {
    // write staged tile (compiler inserts the vmcnt wait)
    *(u16x8*)&Ks[sr * KP + sk]     = kra;
    *(u16x8*)&Ks[sr * KP + sk + 8] = krb;
    *(u16x8*)&Vs[sr * KP + sk]     = vra;
    *(u16x8*)&Vs[sr * KP + sk + 8] = vrb;
    __syncthreads();
    if (nt < 15) {  // issue next tile's loads; latency hides under compute
      const u16* nK = gK + (nt + 1) * 4096;
      const u16* nV = gV + (nt + 1) * 64;
      kra = ((const u16x8*)nK)[0]; krb = ((const u16x8*)nK)[1];
      vra = ((const u16x8*)nV)[0]; vrb = ((const u16x8*)nV)[1];
    }

    __builtin_amdgcn_s_setprio(1);
    #pragma unroll
    for (int mt = 0; mt < 4; mt++) {
      // K-frags for kv rows mt*16+m16 (QK^T A-operand)
      const int krow = (mt * 16 + m16) * KP;
      s16x8 kf0 = *(const s16x8*)&Ks[krow + quad * 8];        // dh 0..31
      s16x8 kf1 = *(const s16x8*)&Ks[krow + 32 + quad * 8];   // dh 32..63
      // V b64 frags for this kv-slice, shared across both q-groups:
      // B[k = mt*16+quad*4+j][col = n*16+m16]
      s16x4 bv4[4];
      #pragma unroll
      for (int n = 0; n < 4; n++)
        bv4[n] = *(const s16x4*)&Vs[(n * 16 + m16) * KP + mt * 16 + quad * 4];
      #pragma unroll
      for (int g = 0; g < 2; g++) {
        // S^T = K @ Q^T: lane(quad,m16) reg r = S[q=g*16+m16][kv=mt*16+quad*4+r]
        f32x4 s = {0.f, 0.f, 0.f, 0.f};
        s = __builtin_amdgcn_mfma_f32_16x16x32_bf16(kf0, aq[g][0], s, 0, 0, 0);
        s = __builtin_amdgcn_mfma_f32_16x16x32_bf16(kf1, aq[g][1], s, 0, 0, 0);
        float e0 = __builtin_amdgcn_exp2f(s[0] * SC);
        float e1 = __builtin_amdgcn_exp2f(s[1] * SC);
        float e2 = __builtin_amdgcn_exp2f(s[2] * SC);
        float e3 = __builtin_amdgcn_exp2f(s[3] * SC);
        // pack as the 16x16x16 A-frag: A[row=m16][k=quad*4+j] = e_j
        union { unsigned u[2]; s16x4 s; } ea;
        ea.u[0] = (unsigned)f2bf_rne(e0) | ((unsigned)f2bf_rne(e1) << 16);
        ea.u[1] = (unsigned)f2bf_rne(e2) | ((unsigned)f2bf_rne(e3) << 16);
        // O += E @ V ; den += E @ ones  (C/D layout matches round-5 epilogue)
        #pragma unroll
        for (int n = 0; n < 4; n++)
          acc_o[g][n] = mfma16_bf16(ea.s, bv4[n], acc_o[g][n]);
        acc_d[g] = mfma16_bf16(ea.s, bones4, acc_d[g]);
      }
    }
    __builtin_amdgcn_s_setprio(0);
    __syncthreads();
  }

  // normalize and write (den row r lives in lane quad*16; broadcast to 16 lanes)
  #pragma unroll
  for (int g = 0; g < 2; g++)
    #pragma unroll
    for (int r = 0; r < 4; r++) {
      float d = __shfl(acc_d[g][r], lane & 48);
      float rinv = 1.0f / d;
      const long orow = base + (long)(qrow0 + g * 16 + quad * 4 + r) * 64;
      #pragma unroll
      for (int n = 0; n < 4; n++)
        Obf[orow + n * 16 + m16] = f2bf_rne(acc_o[g][n][r] * rinv);
    }
}

// ---------------------------------------------------------------------------
// kernel_launch
// ---------------------------------------------------------------------------
extern "C" void kernel_launch(void* const* d_in, const int* in_sizes, int n_in,
                              void* d_out, int out_size, void* d_ws, size_t ws_size,
                              hipStream_t stream) {
  const float* query = (const float*)d_in[0];
  const float* key_  = (const float*)d_in[1];
  const float* value = (const float*)d_in[2];
  // d_in[3], d_in[4]: seq lengths (equal, unused)
  const float* Wq = (const float*)d_in[5];
  const float* bq = (const float*)d_in[6];
  const float* Wk = (const float*)d_in[7];
  const float* bk = (const float*)d_in[8];
  const float* Wv = (const float*)d_in[9];
  const float* bv = (const float*)d_in[10];
  const float* Wo = (const float*)d_in[11];
  const float* bo = (const float*)d_in[12];

  char* ws = (char*)d_ws;
  const size_t FUSED_NEED = 104ull << 20;

  if (ws_size >= FUSED_NEED) {
    // Fused layout (104 MB):
    //   [0,8)    Wbf (4 matrices)
    //   [8,56)   QKV: Q [8,24) K [24,40) V [40,56)
    //   [56,104) X3 (bf16 q,k,v inputs); Vt overlays [56,72) after proj GEMM
    //   Obf overlays V [40,56) after transpose
    u16* Wbf = (u16*)(ws);
    u16* QKV = (u16*)(ws + (8l << 20));
    u16* Qbf = QKV;
    u16* Kbf = QKV + 1 * (TOTAL * (long)DMODEL);
    u16* Vbf = QKV + 2 * (TOTAL * (long)DMODEL);
    u16* X3  = (u16*)(ws + (56l << 20));
    u16* Vt  = X3;    // X dead after proj GEMM
    u16* Obf = Vbf;   // V natural dead after transpose

    cvt8_w4<<<dim3(512, 4), 256, 0, stream>>>(Wq, Wk, Wv, Wo, Wbf);
    cvt8_x3<<<dim3(4096, 3), 256, 0, stream>>>(query, key_, value, X3);
    gemm256_qkv<<<dim3(256, 3), 512, 0, stream>>>(X3, Wbf, bq, bk, bv, QKV);
    transpose_v<<<dim3(16, 128), 256, 0, stream>>>(Vbf, Vt);
    attn_kernel<<<dim3(128, 8), 256, 0, stream>>>(Qbf, Kbf, Vt, Obf);
    gemm256_nt<false><<<dim3(256), 512, 0, stream>>>(Obf, Wbf + 3 * 1048576, bo, (float*)d_out);
  } else {
    // Serial fallback (72 MB, proven): Xbf reused for q/k/v in turn.
    u16* Wbf = (u16*)(ws);
    u16* Xbf = (u16*)(ws + (8l << 20));
    u16* Qbf = (u16*)(ws + (24l << 20));
    u16* Kbf = (u16*)(ws + (40l << 20));
    u16* Vbf = (u16*)(ws + (56l << 20));
    u16* Vt  = Xbf;
    u16* Obf = Vbf;

    cvt8_w4<<<dim3(512, 4), 256, 0, stream>>>(Wq, Wk, Wv, Wo, Wbf);
    cvt8<<<4096, 256, 0, stream>>>(query, Xbf);
    gemm256_nt<true><<<dim3(256), 512, 0, stream>>>(Xbf, Wbf + 0 * 1048576, bq, Qbf);
    cvt8<<<4096, 256, 0, stream>>>(key_, Xbf);
    gemm256_nt<true><<<dim3(256), 512, 0, stream>>>(Xbf, Wbf + 1 * 1048576, bk, Kbf);
    cvt8<<<4096, 256, 0, stream>>>(value, Xbf);
    gemm256_nt<true><<<dim3(256), 512, 0, stream>>>(Xbf, Wbf + 2 * 1048576, bv, Vbf);
    transpose_v<<<dim3(16, 128), 256, 0, stream>>>(Vbf, Vt);
    attn_kernel<<<dim3(128, 8), 256, 0, stream>>>(Qbf, Kbf, Vt, Obf);
    gemm256_nt<false><<<dim3(256), 512, 0, stream>>>(Obf, Wbf + 3 * 1048576, bo, (float*)d_out);
  }
}

// Round 7
// 302.559 us; speedup vs baseline: 1.0573x; 1.0573x over previous
//
#include <hip/hip_runtime.h>
#include <hip/hip_bf16.h>

// Problem constants (fixed by the reference)
#define TOTAL   8192
#define DMODEL  1024
#define NHEADS  16
#define NSEQ    8
#define DH      64
// attention block (h,b): contiguous 1024x64 chunk at flat offset hb*65536

// softmax scale folded into Q at projection time: scale * log2(e)
#define QSCALE  (0.125f * 1.44269504088896340736f)

typedef float  f32x4 __attribute__((ext_vector_type(4)));
typedef short  s16x8 __attribute__((ext_vector_type(8)));   // 8 bf16 (4 VGPRs)
typedef unsigned short u16;
typedef u16    u16x8 __attribute__((ext_vector_type(8)));
typedef unsigned u32x2 __attribute__((ext_vector_type(2)));

__device__ __forceinline__ u16 f2bf_rne(float x) {
  union { float f; unsigned u; } v; v.f = x;
  unsigned r = v.u + 0x7FFFu + ((v.u >> 16) & 1u);
  return (u16)(r >> 16);
}

// async global->LDS, 16 B per lane; LDS dest = wave-uniform base + lane*16
__device__ __forceinline__ void async_cp16(const u16* g, u16* l) {
  __builtin_amdgcn_global_load_lds(
      (const __attribute__((address_space(1))) unsigned int*)g,
      (__attribute__((address_space(3))) unsigned int*)l, 16, 0, 0);
}

// ---------------------------------------------------------------------------
// 0. f32 -> bf16 (RNE) converters
// ---------------------------------------------------------------------------
__device__ __forceinline__ void cvt8_one(const float* __restrict__ src,
                                         u16* __restrict__ dst, long i) {
  float4 a = *reinterpret_cast<const float4*>(src + i);
  float4 b = *reinterpret_cast<const float4*>(src + i + 4);
  u16x8 o;
  o[0] = f2bf_rne(a.x); o[1] = f2bf_rne(a.y); o[2] = f2bf_rne(a.z); o[3] = f2bf_rne(a.w);
  o[4] = f2bf_rne(b.x); o[5] = f2bf_rne(b.y); o[6] = f2bf_rne(b.z); o[7] = f2bf_rne(b.w);
  *reinterpret_cast<u16x8*>(dst + i) = o;
}

__global__ __launch_bounds__(256) void cvt8(const float* __restrict__ src,
                                            u16* __restrict__ dst) {
  cvt8_one(src, dst, ((long)blockIdx.x * 256 + threadIdx.x) * 8);
}

// 4 weight matrices in one launch; blockIdx.y picks the matrix
__global__ __launch_bounds__(256) void cvt8_w4(const float* __restrict__ w0,
                                               const float* __restrict__ w1,
                                               const float* __restrict__ w2,
                                               const float* __restrict__ w3,
                                               u16* __restrict__ dst) {
  const float* srcs[4] = {w0, w1, w2, w3};
  cvt8_one(srcs[blockIdx.y], dst + (long)blockIdx.y * (DMODEL * (long)DMODEL),
           ((long)blockIdx.x * 256 + threadIdx.x) * 8);
}

// 3 X inputs in one launch; blockIdx.y picks
__global__ __launch_bounds__(256) void cvt8_x3(const float* __restrict__ x0,
                                               const float* __restrict__ x1,
                                               const float* __restrict__ x2,
                                               u16* __restrict__ dst) {
  const float* srcs[3] = {x0, x1, x2};
  cvt8_one(srcs[blockIdx.y], dst + (long)blockIdx.y * (TOTAL * (long)DMODEL),
           ((long)blockIdx.x * 256 + threadIdx.x) * 8);
}

// ---------------------------------------------------------------------------
// 1. NT GEMM, 8-phase-lite pipeline (T1+T2+T3/T4+T5):
//    BM=256, BN=128, BK=64. 512 threads = 8 waves (4M x 2N), 64x64 per wave.
//    3-stage LDS pipeline (144 KiB): stage tile t+2 while computing tile t.
//    Counted s_waitcnt vmcnt(6) per K-tile (never 0 in the main loop).
//    T2 XOR-swizzle byte^=(row&7)<<4 on ds_read; inverse swizzle pre-applied
//    to the per-lane GLOBAL source so global_load_lds dest stays linear
//    (rule 21: both-sides-or-neither).
//    oscale: multiplied into (acc + bias) before the store — used to fold
//    the attention softmax scale into Q at projection time.
// ---------------------------------------------------------------------------
// LDS per buffer: A 256x64 u16 = 16384, B 128x64 u16 = 8192 -> 24576 u16.
template<bool OUT_BF16>
__device__ __forceinline__ void gemm256_core(const u16* __restrict__ A,
                                             const u16* __restrict__ B,
                                             const float* __restrict__ bias,
                                             void* __restrict__ Cp,
                                             long bm0, long bn0, u16* lds,
                                             float oscale) {
  const int tid  = threadIdx.x;
  const int lane = tid & 63;
  const int wv   = tid >> 6;        // 0..7
  const int quad = lane >> 4;
  const int m16  = lane & 15;
  const int wm   = (wv >> 1) * 64;  // 4 M-waves
  const int wn   = (wv & 1) * 64;   // 2 N-waves

  // --- staging addresses -------------------------------------------------
  // global_load_lds writes LDS linearly at base + lane*16. Lane L's 16B
  // lands at physical row (L>>3), slot (L&7) of its 8-row line; the READ
  // swizzle is slot^(row&7), so the SOURCE fetches slot (L&7)^(L>>3).
  const int l8   = lane >> 3;
  const int slot = (lane & 7) ^ l8;
  const long g_lane = (long)l8 * DMODEL + slot * 8;
  const u16* Ap = A + (bm0 + wv * 32) * (long)DMODEL + g_lane;  // 4 lines x 8 rows
  const u16* Bp = B + (bn0 + wv * 16) * (long)DMODEL + g_lane;  // 2 lines x 8 rows
  u16* ldsA = lds + wv * (4 * 512);
  u16* ldsB = lds + 16384 + wv * (2 * 512);

  // --- frag read offsets (u16 units), T2-swizzled ------------------------
  // logical (row, col-byte c) lives at row*128 + (c ^ ((row&7)<<4))
  const int swz0 = ((quad * 16)      ^ ((m16 & 7) << 4)) >> 1;  // k-half 0
  const int swz1 = ((64 + quad * 16) ^ ((m16 & 7) << 4)) >> 1;  // k-half 1
  const int aro = (wm + m16) * 64;
  const int bro = 16384 + (wn + m16) * 64;

  f32x4 acc[4][4] = {};

#define STAGE_A(buf, kt) do {                                       \
    _Pragma("unroll")                                               \
    for (int al = 0; al < 4; al++)                                  \
      async_cp16(Ap + (long)(kt) * 64 + al * (8 * DMODEL),          \
                 ldsA + (buf) * 24576 + al * 512);                  \
  } while (0)
#define STAGE_B(buf, kt) do {                                       \
    _Pragma("unroll")                                               \
    for (int bl = 0; bl < 2; bl++)                                  \
      async_cp16(Bp + (long)(kt) * 64 + bl * (8 * DMODEL),          \
                 ldsB + (buf) * 24576 + bl * 512);                  \
  } while (0)

  // prologue: tiles 0 and 1 in flight (12 loads)
  STAGE_A(0, 0); STAGE_B(0, 0);
  STAGE_A(1, 1); STAGE_B(1, 1);

  #pragma unroll
  for (int t = 0; t < 16; t++) {           // NT = DMODEL/64 = 16
    const int cur = t % 3;
    const int stg = (t + 2) % 3;
    // retire tile t's 6 loads (tile t+1's 6 stay in flight); align waves
    if (t < 15) asm volatile("s_waitcnt vmcnt(6)" ::: "memory");
    else        asm volatile("s_waitcnt vmcnt(0)" ::: "memory");
    __builtin_amdgcn_s_barrier();
    asm volatile("" ::: "memory");         // no LDS read hoists above barrier

    const u16* lb = lds + cur * 24576;

    // ---- phase A: B frags + A frags 0..1, MFMA quadrant M01 ----
    if (t < 14) STAGE_A(stg, t + 2);       // buf stg last read at t-1: safe
    s16x8 bf[4][2], af[2][2];
    #pragma unroll
    for (int n = 0; n < 4; n++) {
      bf[n][0] = *(const s16x8*)&lb[bro + n * 1024 + swz0];
      bf[n][1] = *(const s16x8*)&lb[bro + n * 1024 + swz1];
    }
    #pragma unroll
    for (int i = 0; i < 2; i++) {
      af[i][0] = *(const s16x8*)&lb[aro + i * 1024 + swz0];
      af[i][1] = *(const s16x8*)&lb[aro + i * 1024 + swz1];
    }
    asm volatile("s_waitcnt lgkmcnt(0)" ::: "memory");
    __builtin_amdgcn_sched_barrier(0);     // rule 18: pin MFMA after the wait
    __builtin_amdgcn_s_setprio(1);
    #pragma unroll
    for (int i = 0; i < 2; i++)
      #pragma unroll
      for (int n = 0; n < 4; n++) {
        acc[i][n] = __builtin_amdgcn_mfma_f32_16x16x32_bf16(af[i][0], bf[n][0], acc[i][n], 0, 0, 0);
        acc[i][n] = __builtin_amdgcn_mfma_f32_16x16x32_bf16(af[i][1], bf[n][1], acc[i][n], 0, 0, 0);
      }
    __builtin_amdgcn_s_setprio(0);
    __builtin_amdgcn_s_barrier();

    // ---- phase B: A frags 2..3 (B frags reused), MFMA quadrant M23 ----
    if (t < 14) STAGE_B(stg, t + 2);
    s16x8 ag[2][2];
    #pragma unroll
    for (int i = 0; i < 2; i++) {
      ag[i][0] = *(const s16x8*)&lb[aro + (i + 2) * 1024 + swz0];
      ag[i][1] = *(const s16x8*)&lb[aro + (i + 2) * 1024 + swz1];
    }
    asm volatile("s_waitcnt lgkmcnt(0)" ::: "memory");
    __builtin_amdgcn_sched_barrier(0);
    __builtin_amdgcn_s_setprio(1);
    #pragma unroll
    for (int i = 0; i < 2; i++)
      #pragma unroll
      for (int n = 0; n < 4; n++) {
        acc[i + 2][n] = __builtin_amdgcn_mfma_f32_16x16x32_bf16(ag[i][0], bf[n][0], acc[i + 2][n], 0, 0, 0);
        acc[i + 2][n] = __builtin_amdgcn_mfma_f32_16x16x32_bf16(ag[i][1], bf[n][1], acc[i + 2][n], 0, 0, 0);
      }
    __builtin_amdgcn_s_setprio(0);
    // no trailing barrier: next iteration's vmcnt+barrier is the fence
  }
#undef STAGE_A
#undef STAGE_B

  // Epilogue. C/D layout (verified m89/m91): col = lane&15, row = quad*4 + reg.
  #pragma unroll
  for (int n = 0; n < 4; n++) {
    const long col = bn0 + wn + n * 16 + m16;
    const float bj = bias[col];
    #pragma unroll
    for (int i = 0; i < 4; i++) {
      const long row0 = bm0 + wm + i * 16 + quad * 4;
      #pragma unroll
      for (int r = 0; r < 4; r++) {
        float v = (acc[i][n][r] + bj) * oscale;
        if constexpr (OUT_BF16)
          ((u16*)Cp)[(row0 + r) * DMODEL + col] = f2bf_rne(v);
        else
          ((float*)Cp)[(row0 + r) * DMODEL + col] = v;
      }
    }
  }
}

// T1 XCD swizzle: dispatch index % 8 = XCD; give each XCD a contiguous
// 32-wg chunk = 4 M-panels x all 8 N-blocks (A 2MB + B 2MB fits 4MB L2).
__device__ __forceinline__ void decode_wg(int x, long& bm0, long& bn0) {
  const int wg = (x & 7) * 32 + (x >> 3);   // bijective: 256 = 8*32
  bm0 = (long)(wg >> 3) * 256;              // 32 M-blocks
  bn0 = (long)(wg & 7) * 128;               // 8 N-blocks
}

template<bool OUT_BF16>
__global__ __launch_bounds__(512, 2) void gemm256_nt(const u16* __restrict__ A,
                                                     const u16* __restrict__ B,
                                                     const float* __restrict__ bias,
                                                     void* __restrict__ Cp,
                                                     float oscale) {
  __shared__ __align__(1024) u16 lds[3 * 24576];  // 144 KiB
  long bm0, bn0;
  decode_wg(blockIdx.x, bm0, bn0);
  gemm256_core<OUT_BF16>(A, B, bias, Cp, bm0, bn0, lds, oscale);
}

// Fused Q/K/V projection: blockIdx.y picks (X, W, bias, out). 768 blocks
// = 3 perfect rounds on 256 CUs. Q output (z==0) pre-scaled by QSCALE.
__global__ __launch_bounds__(512, 2) void gemm256_qkv(const u16* __restrict__ X3,
                                                      const u16* __restrict__ W3,
                                                      const float* __restrict__ bq,
                                                      const float* __restrict__ bk,
                                                      const float* __restrict__ bv,
                                                      u16* __restrict__ QKV) {
  __shared__ __align__(1024) u16 lds[3 * 24576];
  const int z = blockIdx.y;
  const float* bias = (z == 0) ? bq : (z == 1) ? bk : bv;
  const float oscale = (z == 0) ? QSCALE : 1.0f;
  long bm0, bn0;
  decode_wg(blockIdx.x, bm0, bn0);
  gemm256_core<true>(X3 + (long)z * (TOTAL * (long)DMODEL),
                     W3 + (long)z * (DMODEL * (long)DMODEL),
                     bias,
                     QKV + (long)z * (TOTAL * (long)DMODEL),
                     bm0, bn0, lds, oscale);
}

// ---------------------------------------------------------------------------
// 2. Per-block V transpose: Vbf natural (hb-block rows k, cols dh) ->
//    Vt[hb][dh][k] so attention PV B-frags are contiguous ds_read_b128.
// ---------------------------------------------------------------------------
__global__ __launch_bounds__(256) void transpose_v(const u16* __restrict__ Vbf,
                                                   u16* __restrict__ Vt) {
  constexpr int TP = 72;
  __shared__ u16 tile[64 * TP];  // tile[dh][k]
  const int tid = threadIdx.x;
  const long base = (long)blockIdx.y * 65536;  // hb block
  const int kt = blockIdx.x;                   // 16 k-tiles of 64
  {
    int k = tid >> 2, dh0 = (tid & 3) * 16;
    const u16* g = Vbf + base + (long)(kt * 64 + k) * 64 + dh0;
    u16x8 a = ((const u16x8*)g)[0];
    u16x8 b = ((const u16x8*)g)[1];
    #pragma unroll
    for (int i = 0; i < 8; i++) tile[(dh0 + i) * TP + k] = a[i];
    #pragma unroll
    for (int i = 0; i < 8; i++) tile[(dh0 + 8 + i) * TP + k] = b[i];
  }
  __syncthreads();
  {
    int dh = tid >> 2, k0 = (tid & 3) * 16;
    u16x8 a = *(const u16x8*)&tile[dh * TP + k0];
    u16x8 b = *(const u16x8*)&tile[dh * TP + k0 + 8];
    u16* g = Vt + base + (long)dh * 1024 + kt * 64 + k0;
    ((u16x8*)g)[0] = a;
    ((u16x8*)g)[1] = b;
  }
}

// ---------------------------------------------------------------------------
// 3. Attention: per (hb, 128-row q-tile). 4 waves x 32 Q-rows (2 groups of 16).
//    K/V tiles of 64 in LDS (pitch 72, round-5 verified layout).
//    No max-subtraction (scores bounded): acc_o = sum e^(s)*V (Q pre-scaled
//    by QSCALE at projection), den via ones-MFMA.
//    SWAPPED QK^T: S^T = mfma(A=K_frag, B=Q_frag) puts 4 consecutive kv
//    (fixed q) in each lane's C-layout regs -> round-half-up pack (2 ops/val;
//    differs from RNE only on exact ties) -> one ds_write_b64 into Es[q][kv].
//    E read-back as PV A-frags: byte-identical to round-1/5 (verified).
//    VALU diet vs round-5: -32 v_mul (prescale) and -~2 ops/val (pack) per
//    tile per wave — attacks the measured VALU-issue bound (VALUBusy 48-59%).
//    T14: next tile's K/V global loads issue right after the staging barrier.
//    Grid: x = hb (128) -> same-hb blocks land on one XCD (128 % 8 == 0).
// ---------------------------------------------------------------------------
__global__ __launch_bounds__(256) void attn_kernel(const u16* __restrict__ Qbf,
                                                   const u16* __restrict__ Kbf,
                                                   const u16* __restrict__ Vt,
                                                   u16* __restrict__ Obf) {
  constexpr int KP = 72;  // uniform pitch: frag reads/writes are 2-way (free)
  __shared__ u16 Ks[64 * KP];        // Ks[kv][dh]
  __shared__ u16 Vs[64 * KP];        // Vs[dh][kv]
  __shared__ u16 Es[4 * 32 * KP];    // per-wave E[q(32)][kv(64)]
  const int tid  = threadIdx.x;
  const int lane = tid & 63;
  const int wv   = tid >> 6;
  const int quad = lane >> 4;
  const int m16  = lane & 15;
  const int qt   = blockIdx.y;                 // 8 q-tiles of 128
  const long base = (long)blockIdx.x * 65536;  // hb block

  const int qrow0 = qt * 128 + wv * 32;
  s16x8 aq[2][2];
  #pragma unroll
  for (int g = 0; g < 2; g++)
    #pragma unroll
    for (int s = 0; s < 2; s++)
      aq[g][s] = *(const s16x8*)(Qbf + base + (long)(qrow0 + g * 16 + m16) * 64 + s * 32 + quad * 8);

  f32x4 acc_o[2][4] = {};
  f32x4 acc_d[2] = {};

  // ones B-frag: B[k][0]=1 -> D col 0 = row sums of A
  union { u16x8 u; s16x8 s; } onesu;
  u16 ov = (m16 == 0) ? (u16)0x3F80 : (u16)0;
  #pragma unroll
  for (int i = 0; i < 8; i++) onesu.u[i] = ov;
  const s16x8 bones = onesu.s;

  const int sr = tid >> 2;
  const int sk = (tid & 3) * 16;

  // T14 prefetch registers (tile nt staged in regs across the barrier)
  const u16* gK = Kbf + base + (long)sr * 64 + sk;     // + nt*4096
  const u16* gV = Vt  + base + (long)sr * 1024 + sk;   // + nt*64
  u16x8 kra = ((const u16x8*)gK)[0], krb = ((const u16x8*)gK)[1];
  u16x8 vra = ((const u16x8*)gV)[0], vrb = ((const u16x8*)gV)[1];

  for (int nt = 0; nt < 16; nt++) {
    // write staged tile (compiler inserts the vmcnt wait)
    *(u16x8*)&Ks[sr * KP + sk]     = kra;
    *(u16x8*)&Ks[sr * KP + sk + 8] = krb;
    *(u16x8*)&Vs[sr * KP + sk]     = vra;
    *(u16x8*)&Vs[sr * KP + sk + 8] = vrb;
    __syncthreads();
    if (nt < 15) {  // issue next tile's loads; latency hides under compute
      const u16* nK = gK + (nt + 1) * 4096;
      const u16* nV = gV + (nt + 1) * 64;
      kra = ((const u16x8*)nK)[0]; krb = ((const u16x8*)nK)[1];
      vra = ((const u16x8*)nV)[0]; vrb = ((const u16x8*)nV)[1];
    }

    // S^T = K @ Q^T (swapped operands): lane (quad,m16) gets
    // s[r] = S[q = g*16+m16][kv = mt*16 + quad*4 + r]  -> 4 consecutive kv.
    // E = exp2(S) (Q pre-scaled) -> RHU pack -> one b64 write into Es[q][kv].
    #pragma unroll
    for (int mt = 0; mt < 4; mt++) {
      const int krow = (mt * 16 + m16) * KP;
      s16x8 kf0 = *(const s16x8*)&Ks[krow + quad * 8];        // dh 0..31 slice
      s16x8 kf1 = *(const s16x8*)&Ks[krow + 32 + quad * 8];   // dh 32..63 slice
      #pragma unroll
      for (int g = 0; g < 2; g++) {
        f32x4 s = {0.f, 0.f, 0.f, 0.f};
        s = __builtin_amdgcn_mfma_f32_16x16x32_bf16(kf0, aq[g][0], s, 0, 0, 0);
        s = __builtin_amdgcn_mfma_f32_16x16x32_bf16(kf1, aq[g][1], s, 0, 0, 0);
        float e0 = __builtin_amdgcn_exp2f(s[0]);
        float e1 = __builtin_amdgcn_exp2f(s[1]);
        float e2 = __builtin_amdgcn_exp2f(s[2]);
        float e3 = __builtin_amdgcn_exp2f(s[3]);
        // round-half-up f32->bf16 pack: 2 VALU ops/value
        unsigned a0 = __float_as_uint(e0) + 0x8000u;
        unsigned a1 = __float_as_uint(e1) + 0x8000u;
        unsigned a2 = __float_as_uint(e2) + 0x8000u;
        unsigned a3 = __float_as_uint(e3) + 0x8000u;
        u32x2 w;
        w.x = (a0 >> 16) | (a1 & 0xFFFF0000u);
        w.y = (a2 >> 16) | (a3 & 0xFFFF0000u);
        *(u32x2*)&Es[(wv * 32 + g * 16 + m16) * KP + mt * 16 + quad * 4] = w;
      }
    }
    // fence: Es b64 writes must complete & order before the b128 re-reads
    asm volatile("s_waitcnt lgkmcnt(0)" ::: "memory");
    __builtin_amdgcn_sched_barrier(0);

    // re-read E as A-frags (round-1/5 path, byte-identical addressing)
    s16x8 ae[2][2];
    #pragma unroll
    for (int g = 0; g < 2; g++) {
      ae[g][0] = *(const s16x8*)&Es[(wv * 32 + g * 16 + m16) * KP + quad * 8];
      ae[g][1] = *(const s16x8*)&Es[(wv * 32 + g * 16 + m16) * KP + 32 + quad * 8];
    }
    // O += E @ V ; den += E @ ones. V frags read once, reused for both groups.
    __builtin_amdgcn_s_setprio(1);
    #pragma unroll
    for (int n = 0; n < 4; n++) {
      s16x8 bv0 = *(const s16x8*)&Vs[(n * 16 + m16) * KP + quad * 8];
      s16x8 bv1 = *(const s16x8*)&Vs[(n * 16 + m16) * KP + 32 + quad * 8];
      #pragma unroll
      for (int g = 0; g < 2; g++) {
        acc_o[g][n] = __builtin_amdgcn_mfma_f32_16x16x32_bf16(ae[g][0], bv0, acc_o[g][n], 0, 0, 0);
        acc_o[g][n] = __builtin_amdgcn_mfma_f32_16x16x32_bf16(ae[g][1], bv1, acc_o[g][n], 0, 0, 0);
      }
    }
    #pragma unroll
    for (int g = 0; g < 2; g++) {
      acc_d[g] = __builtin_amdgcn_mfma_f32_16x16x32_bf16(ae[g][0], bones, acc_d[g], 0, 0, 0);
      acc_d[g] = __builtin_amdgcn_mfma_f32_16x16x32_bf16(ae[g][1], bones, acc_d[g], 0, 0, 0);
    }
    __builtin_amdgcn_s_setprio(0);
    __syncthreads();
  }

  // normalize and write (den row r lives in lane quad*16; broadcast to 16 lanes)
  #pragma unroll
  for (int g = 0; g < 2; g++)
    #pragma unroll
    for (int r = 0; r < 4; r++) {
      float d = __shfl(acc_d[g][r], lane & 48);
      float rinv = 1.0f / d;
      const long orow = base + (long)(qrow0 + g * 16 + quad * 4 + r) * 64;
      #pragma unroll
      for (int n = 0; n < 4; n++)
        Obf[orow + n * 16 + m16] = f2bf_rne(acc_o[g][n][r] * rinv);
    }
}

// ---------------------------------------------------------------------------
// kernel_launch
// ---------------------------------------------------------------------------
extern "C" void kernel_launch(void* const* d_in, const int* in_sizes, int n_in,
                              void* d_out, int out_size, void* d_ws, size_t ws_size,
                              hipStream_t stream) {
  const float* query = (const float*)d_in[0];
  const float* key_  = (const float*)d_in[1];
  const float* value = (const float*)d_in[2];
  // d_in[3], d_in[4]: seq lengths (equal, unused)
  const float* Wq = (const float*)d_in[5];
  const float* bq = (const float*)d_in[6];
  const float* Wk = (const float*)d_in[7];
  const float* bk = (const float*)d_in[8];
  const float* Wv = (const float*)d_in[9];
  const float* bv = (const float*)d_in[10];
  const float* Wo = (const float*)d_in[11];
  const float* bo = (const float*)d_in[12];

  char* ws = (char*)d_ws;
  const size_t FUSED_NEED = 104ull << 20;

  if (ws_size >= FUSED_NEED) {
    // Fused layout (104 MB):
    //   [0,8)    Wbf (4 matrices)
    //   [8,56)   QKV: Q [8,24) K [24,40) V [40,56)
    //   [56,104) X3 (bf16 q,k,v inputs); Vt overlays [56,72) after proj GEMM
    //   Obf overlays V [40,56) after transpose
    u16* Wbf = (u16*)(ws);
    u16* QKV = (u16*)(ws + (8l << 20));
    u16* Qbf = QKV;
    u16* Kbf = QKV + 1 * (TOTAL * (long)DMODEL);
    u16* Vbf = QKV + 2 * (TOTAL * (long)DMODEL);
    u16* X3  = (u16*)(ws + (56l << 20));
    u16* Vt  = X3;    // X dead after proj GEMM
    u16* Obf = Vbf;   // V natural dead after transpose

    cvt8_w4<<<dim3(512, 4), 256, 0, stream>>>(Wq, Wk, Wv, Wo, Wbf);
    cvt8_x3<<<dim3(4096, 3), 256, 0, stream>>>(query, key_, value, X3);
    gemm256_qkv<<<dim3(256, 3), 512, 0, stream>>>(X3, Wbf, bq, bk, bv, QKV);
    transpose_v<<<dim3(16, 128), 256, 0, stream>>>(Vbf, Vt);
    attn_kernel<<<dim3(128, 8), 256, 0, stream>>>(Qbf, Kbf, Vt, Obf);
    gemm256_nt<false><<<dim3(256), 512, 0, stream>>>(Obf, Wbf + 3 * 1048576, bo, (float*)d_out, 1.0f);
  } else {
    // Serial fallback (72 MB, proven): Xbf reused for q/k/v in turn.
    u16* Wbf = (u16*)(ws);
    u16* Xbf = (u16*)(ws + (8l << 20));
    u16* Qbf = (u16*)(ws + (24l << 20));
    u16* Kbf = (u16*)(ws + (40l << 20));
    u16* Vbf = (u16*)(ws + (56l << 20));
    u16* Vt  = Xbf;
    u16* Obf = Vbf;

    cvt8_w4<<<dim3(512, 4), 256, 0, stream>>>(Wq, Wk, Wv, Wo, Wbf);
    cvt8<<<4096, 256, 0, stream>>>(query, Xbf);
    gemm256_nt<true><<<dim3(256), 512, 0, stream>>>(Xbf, Wbf + 0 * 1048576, bq, Qbf, QSCALE);
    cvt8<<<4096, 256, 0, stream>>>(key_, Xbf);
    gemm256_nt<true><<<dim3(256), 512, 0, stream>>>(Xbf, Wbf + 1 * 1048576, bk, Kbf, 1.0f);
    cvt8<<<4096, 256, 0, stream>>>(value, Xbf);
    gemm256_nt<true><<<dim3(256), 512, 0, stream>>>(Xbf, Wbf + 2 * 1048576, bv, Vbf, 1.0f);
    transpose_v<<<dim3(16, 128), 256, 0, stream>>>(Vbf, Vt);
    attn_kernel<<<dim3(128, 8), 256, 0, stream>>>(Qbf, Kbf, Vt, Obf);
    gemm256_nt<false><<<dim3(256), 512, 0, stream>>>(Obf, Wbf + 3 * 1048576, bo, (float*)d_out, 1.0f);
  }
}

// Round 9
// 299.864 us; speedup vs baseline: 1.0668x; 1.0090x over previous
//
#include <hip/hip_runtime.h>
#include <hip/hip_bf16.h>

// Problem constants (fixed by the reference)
#define TOTAL   8192
#define DMODEL  1024
#define NHEADS  16
#define NSEQ    8
#define DH      64
// attention block (h,b): contiguous 1024x64 chunk at flat offset hb*65536
// (raw-view reshape semantics: head h takes ROW-bands of the projection
// output — NOT columns. Verified by rounds 0-7; round 8's column-mapped
// fused transpose violated this and failed.)

// softmax scale folded into Q at projection time: scale * log2(e)
#define QSCALE  (0.125f * 1.44269504088896340736f)

typedef float  f32x4 __attribute__((ext_vector_type(4)));
typedef short  s16x8 __attribute__((ext_vector_type(8)));   // 8 bf16 (4 VGPRs)
typedef unsigned short u16;
typedef u16    u16x8 __attribute__((ext_vector_type(8)));
typedef unsigned u32x2 __attribute__((ext_vector_type(2)));

__device__ __forceinline__ u16 f2bf_rne(float x) {
  union { float f; unsigned u; } v; v.f = x;
  unsigned r = v.u + 0x7FFFu + ((v.u >> 16) & 1u);
  return (u16)(r >> 16);
}

// async global->LDS, 16 B per lane; LDS dest = wave-uniform base + lane*16
__device__ __forceinline__ void async_cp16(const u16* g, u16* l) {
  __builtin_amdgcn_global_load_lds(
      (const __attribute__((address_space(1))) unsigned int*)g,
      (__attribute__((address_space(3))) unsigned int*)l, 16, 0, 0);
}

// ---------------------------------------------------------------------------
// 0. f32 -> bf16 (RNE) converters
// ---------------------------------------------------------------------------
__device__ __forceinline__ void cvt8_one(const float* __restrict__ src,
                                         u16* __restrict__ dst, long i) {
  float4 a = *reinterpret_cast<const float4*>(src + i);
  float4 b = *reinterpret_cast<const float4*>(src + i + 4);
  u16x8 o;
  o[0] = f2bf_rne(a.x); o[1] = f2bf_rne(a.y); o[2] = f2bf_rne(a.z); o[3] = f2bf_rne(a.w);
  o[4] = f2bf_rne(b.x); o[5] = f2bf_rne(b.y); o[6] = f2bf_rne(b.z); o[7] = f2bf_rne(b.w);
  *reinterpret_cast<u16x8*>(dst + i) = o;
}

__global__ __launch_bounds__(256) void cvt8(const float* __restrict__ src,
                                            u16* __restrict__ dst) {
  cvt8_one(src, dst, ((long)blockIdx.x * 256 + threadIdx.x) * 8);
}

// 4 weight matrices in one launch; blockIdx.y picks the matrix
__global__ __launch_bounds__(256) void cvt8_w4(const float* __restrict__ w0,
                                               const float* __restrict__ w1,
                                               const float* __restrict__ w2,
                                               const float* __restrict__ w3,
                                               u16* __restrict__ dst) {
  const float* srcs[4] = {w0, w1, w2, w3};
  cvt8_one(srcs[blockIdx.y], dst + (long)blockIdx.y * (DMODEL * (long)DMODEL),
           ((long)blockIdx.x * 256 + threadIdx.x) * 8);
}

// Merged X3 + W4 conversion: one launch instead of two (stream-serialized
// before). Blocks [0,12288) convert the 3 X inputs; [12288,14336) the 4 Ws.
__global__ __launch_bounds__(256) void cvt8_all(const float* __restrict__ x0,
                                                const float* __restrict__ x1,
                                                const float* __restrict__ x2,
                                                const float* __restrict__ w0,
                                                const float* __restrict__ w1,
                                                const float* __restrict__ w2,
                                                const float* __restrict__ w3,
                                                u16* __restrict__ X3,
                                                u16* __restrict__ Wbf) {
  const int bid = blockIdx.x;
  if (bid < 3 * 4096) {
    const int z = bid >> 12;
    const float* srcs[3] = {x0, x1, x2};
    cvt8_one(srcs[z], X3 + (long)z * (TOTAL * (long)DMODEL),
             ((long)(bid & 4095) * 256 + threadIdx.x) * 8);
  } else {
    const int b2 = bid - 3 * 4096;
    const int z = b2 >> 9;
    const float* srcs[4] = {w0, w1, w2, w3};
    cvt8_one(srcs[z], Wbf + (long)z * (DMODEL * (long)DMODEL),
             ((long)(b2 & 511) * 256 + threadIdx.x) * 8);
  }
}

// ---------------------------------------------------------------------------
// 1. NT GEMM, 8-phase-lite pipeline (T1+T2+T3/T4+T5):
//    BM=256, BN=128, BK=64. 512 threads = 8 waves (4M x 2N), 64x64 per wave.
//    3-stage LDS pipeline (144 KiB): stage tile t+2 while computing tile t.
//    Counted s_waitcnt vmcnt(6) per K-tile (never 0 in the main loop).
//    T2 XOR-swizzle byte^=(row&7)<<4 on ds_read; inverse swizzle pre-applied
//    to the per-lane GLOBAL source so global_load_lds dest stays linear.
//    oscale: multiplied into (acc + bias) before the store — folds the
//    attention softmax scale into Q at projection time.
// ---------------------------------------------------------------------------
// LDS per buffer: A 256x64 u16 = 16384, B 128x64 u16 = 8192 -> 24576 u16.
template<bool OUT_BF16>
__device__ __forceinline__ void gemm256_core(const u16* __restrict__ A,
                                             const u16* __restrict__ B,
                                             const float* __restrict__ bias,
                                             void* __restrict__ Cp,
                                             long bm0, long bn0, u16* lds,
                                             float oscale) {
  const int tid  = threadIdx.x;
  const int lane = tid & 63;
  const int wv   = tid >> 6;        // 0..7
  const int quad = lane >> 4;
  const int m16  = lane & 15;
  const int wm   = (wv >> 1) * 64;  // 4 M-waves
  const int wn   = (wv & 1) * 64;   // 2 N-waves

  const int l8   = lane >> 3;
  const int slot = (lane & 7) ^ l8;
  const long g_lane = (long)l8 * DMODEL + slot * 8;
  const u16* Ap = A + (bm0 + wv * 32) * (long)DMODEL + g_lane;  // 4 lines x 8 rows
  const u16* Bp = B + (bn0 + wv * 16) * (long)DMODEL + g_lane;  // 2 lines x 8 rows
  u16* ldsA = lds + wv * (4 * 512);
  u16* ldsB = lds + 16384 + wv * (2 * 512);

  const int swz0 = ((quad * 16)      ^ ((m16 & 7) << 4)) >> 1;  // k-half 0
  const int swz1 = ((64 + quad * 16) ^ ((m16 & 7) << 4)) >> 1;  // k-half 1
  const int aro = (wm + m16) * 64;
  const int bro = 16384 + (wn + m16) * 64;

  f32x4 acc[4][4] = {};

#define STAGE_A(buf, kt) do {                                       \
    _Pragma("unroll")                                               \
    for (int al = 0; al < 4; al++)                                  \
      async_cp16(Ap + (long)(kt) * 64 + al * (8 * DMODEL),          \
                 ldsA + (buf) * 24576 + al * 512);                  \
  } while (0)
#define STAGE_B(buf, kt) do {                                       \
    _Pragma("unroll")                                               \
    for (int bl = 0; bl < 2; bl++)                                  \
      async_cp16(Bp + (long)(kt) * 64 + bl * (8 * DMODEL),          \
                 ldsB + (buf) * 24576 + bl * 512);                  \
  } while (0)

  // prologue: tiles 0 and 1 in flight (12 loads)
  STAGE_A(0, 0); STAGE_B(0, 0);
  STAGE_A(1, 1); STAGE_B(1, 1);

  #pragma unroll
  for (int t = 0; t < 16; t++) {           // NT = DMODEL/64 = 16
    const int cur = t % 3;
    const int stg = (t + 2) % 3;
    if (t < 15) asm volatile("s_waitcnt vmcnt(6)" ::: "memory");
    else        asm volatile("s_waitcnt vmcnt(0)" ::: "memory");
    __builtin_amdgcn_s_barrier();
    asm volatile("" ::: "memory");         // no LDS read hoists above barrier

    const u16* lb = lds + cur * 24576;

    // ---- phase A: B frags + A frags 0..1, MFMA quadrant M01 ----
    if (t < 14) STAGE_A(stg, t + 2);       // buf stg last read at t-1: safe
    s16x8 bf[4][2], af[2][2];
    #pragma unroll
    for (int n = 0; n < 4; n++) {
      bf[n][0] = *(const s16x8*)&lb[bro + n * 1024 + swz0];
      bf[n][1] = *(const s16x8*)&lb[bro + n * 1024 + swz1];
    }
    #pragma unroll
    for (int i = 0; i < 2; i++) {
      af[i][0] = *(const s16x8*)&lb[aro + i * 1024 + swz0];
      af[i][1] = *(const s16x8*)&lb[aro + i * 1024 + swz1];
    }
    asm volatile("s_waitcnt lgkmcnt(0)" ::: "memory");
    __builtin_amdgcn_sched_barrier(0);     // rule 18: pin MFMA after the wait
    __builtin_amdgcn_s_setprio(1);
    #pragma unroll
    for (int i = 0; i < 2; i++)
      #pragma unroll
      for (int n = 0; n < 4; n++) {
        acc[i][n] = __builtin_amdgcn_mfma_f32_16x16x32_bf16(af[i][0], bf[n][0], acc[i][n], 0, 0, 0);
        acc[i][n] = __builtin_amdgcn_mfma_f32_16x16x32_bf16(af[i][1], bf[n][1], acc[i][n], 0, 0, 0);
      }
    __builtin_amdgcn_s_setprio(0);
    __builtin_amdgcn_s_barrier();

    // ---- phase B: A frags 2..3 (B frags reused), MFMA quadrant M23 ----
    if (t < 14) STAGE_B(stg, t + 2);
    s16x8 ag[2][2];
    #pragma unroll
    for (int i = 0; i < 2; i++) {
      ag[i][0] = *(const s16x8*)&lb[aro + (i + 2) * 1024 + swz0];
      ag[i][1] = *(const s16x8*)&lb[aro + (i + 2) * 1024 + swz1];
    }
    asm volatile("s_waitcnt lgkmcnt(0)" ::: "memory");
    __builtin_amdgcn_sched_barrier(0);
    __builtin_amdgcn_s_setprio(1);
    #pragma unroll
    for (int i = 0; i < 2; i++)
      #pragma unroll
      for (int n = 0; n < 4; n++) {
        acc[i + 2][n] = __builtin_amdgcn_mfma_f32_16x16x32_bf16(ag[i][0], bf[n][0], acc[i + 2][n], 0, 0, 0);
        acc[i + 2][n] = __builtin_amdgcn_mfma_f32_16x16x32_bf16(ag[i][1], bf[n][1], acc[i + 2][n], 0, 0, 0);
      }
    __builtin_amdgcn_s_setprio(0);
    // no trailing barrier: next iteration's vmcnt+barrier is the fence
  }
#undef STAGE_A
#undef STAGE_B

  // Epilogue. C/D layout (verified m89/m91): col = lane&15, row = quad*4 + reg.
  #pragma unroll
  for (int n = 0; n < 4; n++) {
    const long col = bn0 + wn + n * 16 + m16;
    const float bj = bias[col];
    #pragma unroll
    for (int i = 0; i < 4; i++) {
      const long row0 = bm0 + wm + i * 16 + quad * 4;
      #pragma unroll
      for (int r = 0; r < 4; r++) {
        float v = (acc[i][n][r] + bj) * oscale;
        if constexpr (OUT_BF16)
          ((u16*)Cp)[(row0 + r) * DMODEL + col] = f2bf_rne(v);
        else
          ((float*)Cp)[(row0 + r) * DMODEL + col] = v;
      }
    }
  }
}

// T1 XCD swizzle: dispatch index % 8 = XCD; give each XCD a contiguous
// 32-wg chunk = 4 M-panels x all 8 N-blocks (A 2MB + B 2MB fits 4MB L2).
__device__ __forceinline__ void decode_wg(int x, long& bm0, long& bn0) {
  const int wg = (x & 7) * 32 + (x >> 3);   // bijective: 256 = 8*32
  bm0 = (long)(wg >> 3) * 256;              // 32 M-blocks
  bn0 = (long)(wg & 7) * 128;               // 8 N-blocks
}

template<bool OUT_BF16>
__global__ __launch_bounds__(512, 2) void gemm256_nt(const u16* __restrict__ A,
                                                     const u16* __restrict__ B,
                                                     const float* __restrict__ bias,
                                                     void* __restrict__ Cp,
                                                     float oscale) {
  __shared__ __align__(1024) u16 lds[3 * 24576];  // 144 KiB
  long bm0, bn0;
  decode_wg(blockIdx.x, bm0, bn0);
  gemm256_core<OUT_BF16>(A, B, bias, Cp, bm0, bn0, lds, oscale);
}

// Fused Q/K/V projection: blockIdx.y picks (X, W, bias, out). 768 blocks
// = 3 perfect rounds on 256 CUs. Q output (z==0) pre-scaled by QSCALE.
__global__ __launch_bounds__(512, 2) void gemm256_qkv(const u16* __restrict__ X3,
                                                      const u16* __restrict__ W3,
                                                      const float* __restrict__ bq,
                                                      const float* __restrict__ bk,
                                                      const float* __restrict__ bv,
                                                      u16* __restrict__ QKV) {
  __shared__ __align__(1024) u16 lds[3 * 24576];
  const int z = blockIdx.y;
  const float* bias = (z == 0) ? bq : (z == 1) ? bk : bv;
  const float oscale = (z == 0) ? QSCALE : 1.0f;
  long bm0, bn0;
  decode_wg(blockIdx.x, bm0, bn0);
  gemm256_core<true>(X3 + (long)z * (TOTAL * (long)DMODEL),
                     W3 + (long)z * (DMODEL * (long)DMODEL),
                     bias,
                     QKV + (long)z * (TOTAL * (long)DMODEL),
                     bm0, bn0, lds, oscale);
}

// ---------------------------------------------------------------------------
// 2. Per-block V transpose: Vbf natural (hb-block rows k, cols dh) ->
//    Vt[hb][dh][k] so attention PV B-frags are contiguous ds_read_b128.
// ---------------------------------------------------------------------------
__global__ __launch_bounds__(256) void transpose_v(const u16* __restrict__ Vbf,
                                                   u16* __restrict__ Vt) {
  constexpr int TP = 72;
  __shared__ u16 tile[64 * TP];  // tile[dh][k]
  const int tid = threadIdx.x;
  const long base = (long)blockIdx.y * 65536;  // hb block
  const int kt = blockIdx.x;                   // 16 k-tiles of 64
  {
    int k = tid >> 2, dh0 = (tid & 3) * 16;
    const u16* g = Vbf + base + (long)(kt * 64 + k) * 64 + dh0;
    u16x8 a = ((const u16x8*)g)[0];
    u16x8 b = ((const u16x8*)g)[1];
    #pragma unroll
    for (int i = 0; i < 8; i++) tile[(dh0 + i) * TP + k] = a[i];
    #pragma unroll
    for (int i = 0; i < 8; i++) tile[(dh0 + 8 + i) * TP + k] = b[i];
  }
  __syncthreads();
  {
    int dh = tid >> 2, k0 = (tid & 3) * 16;
    u16x8 a = *(const u16x8*)&tile[dh * TP + k0];
    u16x8 b = *(const u16x8*)&tile[dh * TP + k0 + 8];
    u16* g = Vt + base + (long)dh * 1024 + kt * 64 + k0;
    ((u16x8*)g)[0] = a;
    ((u16x8*)g)[1] = b;
  }
}

// ---------------------------------------------------------------------------
// 3. Attention: per (hb, 256-row q-tile). 512 threads = 8 waves x 32 Q-rows.
//    8 waves share one K/V staging (waves 0-3 stage K, 4-7 stage V — wave-
//    uniform split): K/V HBM reads halve, and 2 blocks/CU co-resident gives
//    4 waves/SIMD (was ~2) to cover the per-tile serial chain.
//    Per-wave math identical to round 7 (proven): swapped QK^T -> 4
//    consecutive kv per lane -> RHU pack -> one ds_write_b64 into per-wave
//    Es[q][kv]; E read-back as PV A-frags; Q pre-scaled by QSCALE; den via
//    ones-MFMA. LDS = Ks 9K + Vs 9K + Es 36.9K = 55.3 KB.
//    Grid: x = hb (128), y = 4 q-tiles of 256.
// ---------------------------------------------------------------------------
__global__ __launch_bounds__(512) void attn_kernel(const u16* __restrict__ Qbf,
                                                   const u16* __restrict__ Kbf,
                                                   const u16* __restrict__ Vt,
                                                   u16* __restrict__ Obf) {
  constexpr int KP = 72;  // uniform pitch: frag reads/writes are 2-way (free)
  __shared__ u16 Ks[64 * KP];        // Ks[kv][dh]
  __shared__ u16 Vs[64 * KP];        // Vs[dh][kv]
  __shared__ u16 Es[8 * 32 * KP];    // per-wave E[q(32)][kv(64)]
  const int tid  = threadIdx.x;
  const int lane = tid & 63;
  const int wv   = tid >> 6;                   // 0..7
  const int quad = lane >> 4;
  const int m16  = lane & 15;
  const int qt   = blockIdx.y;                 // 4 q-tiles of 256
  const long base = (long)blockIdx.x * 65536;  // hb block

  const int qrow0 = qt * 256 + wv * 32;
  s16x8 aq[2][2];
  #pragma unroll
  for (int g = 0; g < 2; g++)
    #pragma unroll
    for (int s = 0; s < 2; s++)
      aq[g][s] = *(const s16x8*)(Qbf + base + (long)(qrow0 + g * 16 + m16) * 64 + s * 32 + quad * 8);

  f32x4 acc_o[2][4] = {};
  f32x4 acc_d[2] = {};

  // ones B-frag: B[k][0]=1 -> D col 0 = row sums of A
  union { u16x8 u; s16x8 s; } onesu;
  u16 ov = (m16 == 0) ? (u16)0x3F80 : (u16)0;
  #pragma unroll
  for (int i = 0; i < 8; i++) onesu.u[i] = ov;
  const s16x8 bones = onesu.s;

  // staging split: waves 0-3 stage K (64x64), waves 4-7 stage V. Wave-uniform.
  const int sr = (tid & 255) >> 2;   // 0..63
  const int sk = (tid & 3) * 16;
  const bool isK = tid < 256;
  const u16* gS = isK ? (Kbf + base + (long)sr * 64 + sk)
                      : (Vt  + base + (long)sr * 1024 + sk);
  const int step = isK ? 4096 : 64;
  u16* lS = (isK ? Ks : Vs) + sr * KP + sk;
  u16x8 ra = ((const u16x8*)gS)[0], rb = ((const u16x8*)gS)[1];

  for (int nt = 0; nt < 16; nt++) {
    // write staged tile (compiler inserts the vmcnt wait)
    *(u16x8*)lS       = ra;
    *(u16x8*)(lS + 8) = rb;
    __syncthreads();
    if (nt < 15) {  // issue next tile's loads; latency hides under compute
      const u16* nS = gS + (long)(nt + 1) * step;
      ra = ((const u16x8*)nS)[0]; rb = ((const u16x8*)nS)[1];
    }

    // S^T = K @ Q^T (swapped operands): lane (quad,m16) gets
    // s[r] = S[q = g*16+m16][kv = mt*16 + quad*4 + r]  -> 4 consecutive kv.
    // E = exp2(S) (Q pre-scaled) -> RHU pack -> one b64 write into Es[q][kv].
    #pragma unroll
    for (int mt = 0; mt < 4; mt++) {
      const int krow = (mt * 16 + m16) * KP;
      s16x8 kf0 = *(const s16x8*)&Ks[krow + quad * 8];        // dh 0..31 slice
      s16x8 kf1 = *(const s16x8*)&Ks[krow + 32 + quad * 8];   // dh 32..63 slice
      #pragma unroll
      for (int g = 0; g < 2; g++) {
        f32x4 s = {0.f, 0.f, 0.f, 0.f};
        s = __builtin_amdgcn_mfma_f32_16x16x32_bf16(kf0, aq[g][0], s, 0, 0, 0);
        s = __builtin_amdgcn_mfma_f32_16x16x32_bf16(kf1, aq[g][1], s, 0, 0, 0);
        float e0 = __builtin_amdgcn_exp2f(s[0]);
        float e1 = __builtin_amdgcn_exp2f(s[1]);
        float e2 = __builtin_amdgcn_exp2f(s[2]);
        float e3 = __builtin_amdgcn_exp2f(s[3]);
        // round-half-up f32->bf16 pack: 2 VALU ops/value
        unsigned a0 = __float_as_uint(e0) + 0x8000u;
        unsigned a1 = __float_as_uint(e1) + 0x8000u;
        unsigned a2 = __float_as_uint(e2) + 0x8000u;
        unsigned a3 = __float_as_uint(e3) + 0x8000u;
        u32x2 w;
        w.x = (a0 >> 16) | (a1 & 0xFFFF0000u);
        w.y = (a2 >> 16) | (a3 & 0xFFFF0000u);
        *(u32x2*)&Es[(wv * 32 + g * 16 + m16) * KP + mt * 16 + quad * 4] = w;
      }
    }
    // fence: Es b64 writes must complete & order before the b128 re-reads
    asm volatile("s_waitcnt lgkmcnt(0)" ::: "memory");
    __builtin_amdgcn_sched_barrier(0);

    // re-read E as A-frags (round-7 path, byte-identical addressing)
    s16x8 ae[2][2];
    #pragma unroll
    for (int g = 0; g < 2; g++) {
      ae[g][0] = *(const s16x8*)&Es[(wv * 32 + g * 16 + m16) * KP + quad * 8];
      ae[g][1] = *(const s16x8*)&Es[(wv * 32 + g * 16 + m16) * KP + 32 + quad * 8];
    }
    // O += E @ V ; den += E @ ones. V frags read once, reused for both groups.
    __builtin_amdgcn_s_setprio(1);
    #pragma unroll
    for (int n = 0; n < 4; n++) {
      s16x8 bv0 = *(const s16x8*)&Vs[(n * 16 + m16) * KP + quad * 8];
      s16x8 bv1 = *(const s16x8*)&Vs[(n * 16 + m16) * KP + 32 + quad * 8];
      #pragma unroll
      for (int g = 0; g < 2; g++) {
        acc_o[g][n] = __builtin_amdgcn_mfma_f32_16x16x32_bf16(ae[g][0], bv0, acc_o[g][n], 0, 0, 0);
        acc_o[g][n] = __builtin_amdgcn_mfma_f32_16x16x32_bf16(ae[g][1], bv1, acc_o[g][n], 0, 0, 0);
      }
    }
    #pragma unroll
    for (int g = 0; g < 2; g++) {
      acc_d[g] = __builtin_amdgcn_mfma_f32_16x16x32_bf16(ae[g][0], bones, acc_d[g], 0, 0, 0);
      acc_d[g] = __builtin_amdgcn_mfma_f32_16x16x32_bf16(ae[g][1], bones, acc_d[g], 0, 0, 0);
    }
    __builtin_amdgcn_s_setprio(0);
    __syncthreads();
  }

  // normalize and write (den row r lives in lane quad*16; broadcast to 16 lanes)
  #pragma unroll
  for (int g = 0; g < 2; g++)
    #pragma unroll
    for (int r = 0; r < 4; r++) {
      float d = __shfl(acc_d[g][r], lane & 48);
      float rinv = 1.0f / d;
      const long orow = base + (long)(qrow0 + g * 16 + quad * 4 + r) * 64;
      #pragma unroll
      for (int n = 0; n < 4; n++)
        Obf[orow + n * 16 + m16] = f2bf_rne(acc_o[g][n][r] * rinv);
    }
}

// ---------------------------------------------------------------------------
// kernel_launch
// ---------------------------------------------------------------------------
extern "C" void kernel_launch(void* const* d_in, const int* in_sizes, int n_in,
                              void* d_out, int out_size, void* d_ws, size_t ws_size,
                              hipStream_t stream) {
  const float* query = (const float*)d_in[0];
  const float* key_  = (const float*)d_in[1];
  const float* value = (const float*)d_in[2];
  // d_in[3], d_in[4]: seq lengths (equal, unused)
  const float* Wq = (const float*)d_in[5];
  const float* bq = (const float*)d_in[6];
  const float* Wk = (const float*)d_in[7];
  const float* bk = (const float*)d_in[8];
  const float* Wv = (const float*)d_in[9];
  const float* bv = (const float*)d_in[10];
  const float* Wo = (const float*)d_in[11];
  const float* bo = (const float*)d_in[12];

  char* ws = (char*)d_ws;
  const size_t FUSED_NEED = 104ull << 20;

  if (ws_size >= FUSED_NEED) {
    // Fused layout (104 MB):
    //   [0,8)    Wbf (4 matrices)
    //   [8,56)   QKV: Q [8,24) K [24,40) V [40,56)
    //   [56,104) X3 (bf16 q,k,v inputs); Vt overlays [56,72) after proj GEMM
    //   Obf overlays V [40,56) after transpose
    u16* Wbf = (u16*)(ws);
    u16* QKV = (u16*)(ws + (8l << 20));
    u16* Qbf = QKV;
    u16* Kbf = QKV + 1 * (TOTAL * (long)DMODEL);
    u16* Vbf = QKV + 2 * (TOTAL * (long)DMODEL);
    u16* X3  = (u16*)(ws + (56l << 20));
    u16* Vt  = X3;    // X dead after proj GEMM
    u16* Obf = Vbf;   // V natural dead after transpose

    cvt8_all<<<14336, 256, 0, stream>>>(query, key_, value, Wq, Wk, Wv, Wo, X3, Wbf);
    gemm256_qkv<<<dim3(256, 3), 512, 0, stream>>>(X3, Wbf, bq, bk, bv, QKV);
    transpose_v<<<dim3(16, 128), 256, 0, stream>>>(Vbf, Vt);
    attn_kernel<<<dim3(128, 4), 512, 0, stream>>>(Qbf, Kbf, Vt, Obf);
    gemm256_nt<false><<<dim3(256), 512, 0, stream>>>(Obf, Wbf + 3 * 1048576, bo, (float*)d_out, 1.0f);
  } else {
    // Serial fallback (72 MB, proven): Xbf reused for q/k/v in turn.
    u16* Wbf = (u16*)(ws);
    u16* Xbf = (u16*)(ws + (8l << 20));
    u16* Qbf = (u16*)(ws + (24l << 20));
    u16* Kbf = (u16*)(ws + (40l << 20));
    u16* Vbf = (u16*)(ws + (56l << 20));
    u16* Vt  = Xbf;
    u16* Obf = Vbf;

    cvt8_w4<<<dim3(512, 4), 256, 0, stream>>>(Wq, Wk, Wv, Wo, Wbf);
    cvt8<<<4096, 256, 0, stream>>>(query, Xbf);
    gemm256_nt<true><<<dim3(256), 512, 0, stream>>>(Xbf, Wbf + 0 * 1048576, bq, Qbf, QSCALE);
    cvt8<<<4096, 256, 0, stream>>>(key_, Xbf);
    gemm256_nt<true><<<dim3(256), 512, 0, stream>>>(Xbf, Wbf + 1 * 1048576, bk, Kbf, 1.0f);
    cvt8<<<4096, 256, 0, stream>>>(value, Xbf);
    gemm256_nt<true><<<dim3(256), 512, 0, stream>>>(Xbf, Wbf + 2 * 1048576, bv, Vbf, 1.0f);
    transpose_v<<<dim3(16, 128), 256, 0, stream>>>(Vbf, Vt);
    attn_kernel<<<dim3(128, 4), 512, 0, stream>>>(Qbf, Kbf, Vt, Obf);
    gemm256_nt<false><<<dim3(256), 512, 0, stream>>>(Obf, Wbf + 3 * 1048576, bo, (float*)d_out, 1.0f);
  }
}